// Round 1
// baseline (7735.773 us; speedup 1.0000x reference)
//
#include <hip/hip_runtime.h>
#include <hip/hip_bf16.h>
#include <math.h>

#define BB 2
#define TT 1024
#define LL 4
#define HH 12
#define DD 768
#define DHH 64
#define FFF 3072
#define VV 50257
#define MM (BB*TT)   // 2048

// ---------------- embedding + sinusoidal PE ----------------
__global__ void embed_kernel(const int* __restrict__ tokens,
                             const float* __restrict__ emb,
                             float* __restrict__ x) {
    int row = blockIdx.x;            // 0..MM-1 = b*TT + t
    int t = row & (TT - 1);
    int tok = tokens[row];
    for (int d = threadIdx.x; d < DD; d += blockDim.x) {
        int i2 = d & ~1;
        float freq = expf((float)i2 * (-9.210340371976184f / (float)DD));
        float ang = (float)t * freq;
        float pe = (d & 1) ? cosf(ang) : sinf(ang);
        x[(size_t)row * DD + d] = emb[(size_t)tok * DD + d] + pe;
    }
}

// ---------------- layernorm ----------------
__global__ void ln_kernel(const float* __restrict__ x,
                          const float* __restrict__ g,
                          const float* __restrict__ b,
                          float* __restrict__ out) {
    int row = blockIdx.x;
    const float* xr = x + (size_t)row * DD;
    __shared__ float red[256];
    int tid = threadIdx.x;
    float s = 0.f;
    for (int d = tid; d < DD; d += 256) s += xr[d];
    red[tid] = s; __syncthreads();
    for (int w = 128; w > 0; w >>= 1) { if (tid < w) red[tid] += red[tid + w]; __syncthreads(); }
    float mu = red[0] / (float)DD;
    __syncthreads();
    float s2 = 0.f;
    for (int d = tid; d < DD; d += 256) { float t0 = xr[d] - mu; s2 += t0 * t0; }
    red[tid] = s2; __syncthreads();
    for (int w = 128; w > 0; w >>= 1) { if (tid < w) red[tid] += red[tid + w]; __syncthreads(); }
    float rstd = rsqrtf(red[0] / (float)DD + 1e-5f);
    for (int d = tid; d < DD; d += 256)
        out[(size_t)row * DD + d] = (xr[d] - mu) * rstd * g[d] + b[d];
}

// ---------------- rmsnorm ----------------
__global__ void rms_kernel(const float* __restrict__ x,
                           const float* __restrict__ w,
                           float* __restrict__ out) {
    int row = blockIdx.x;
    const float* xr = x + (size_t)row * DD;
    __shared__ float red[256];
    int tid = threadIdx.x;
    float s2 = 0.f;
    for (int d = tid; d < DD; d += 256) { float t0 = xr[d]; s2 += t0 * t0; }
    red[tid] = s2; __syncthreads();
    for (int w2 = 128; w2 > 0; w2 >>= 1) { if (tid < w2) red[tid] += red[tid + w2]; __syncthreads(); }
    float rstd = rsqrtf(red[0] / (float)DD + 1e-6f);
    for (int d = tid; d < DD; d += 256)
        out[(size_t)row * DD + d] = xr[d] * rstd * w[d];
}

// ---------------- generic fp32 tiled GEMM ----------------
// C[m,n] = op(A[M,K] @ B + bias [+ res])
// HEADWISE: B is wq[l]-style [H][K][64]; tile columns (64-wide) align with heads.
template<bool HEADWISE, bool RELU, bool RES>
__global__ void gemm_kernel(const float* __restrict__ A, const float* __restrict__ Bm,
                            const float* __restrict__ bias, const float* __restrict__ res,
                            float* __restrict__ C, int Mdim, int Ndim, int Kdim) {
    __shared__ float As[16][68];   // padded: +4 keeps 16B alignment, kills write conflicts
    __shared__ float Bs[16][64];
    int n0 = blockIdx.x * 64;
    int m0 = blockIdx.y * 64;
    int tid = threadIdx.x;          // 0..255
    const float* Bbase;
    size_t ldb;
    if (HEADWISE) { Bbase = Bm + (size_t)(n0 >> 6) * Kdim * 64; ldb = 64; }
    else          { Bbase = Bm + n0; ldb = (size_t)Ndim; }

    float acc[4][4] = {};
    int tx = tid & 15, ty = tid >> 4;
    int arow  = tid >> 2;           // 0..63
    int acol4 = (tid & 3) * 4;      // 0,4,8,12
    int brow  = tid >> 4;           // 0..15
    int bcol4 = (tid & 15) * 4;     // 0..60
    bool bfull = HEADWISE || (n0 + 64 <= Ndim);

    for (int k0 = 0; k0 < Kdim; k0 += 16) {
        float4 av = *(const float4*)(A + (size_t)(m0 + arow) * Kdim + k0 + acol4);
        As[acol4 + 0][arow] = av.x;
        As[acol4 + 1][arow] = av.y;
        As[acol4 + 2][arow] = av.z;
        As[acol4 + 3][arow] = av.w;
        if (bfull) {
            float4 bv = *(const float4*)(Bbase + (size_t)(k0 + brow) * ldb + bcol4);
            *(float4*)&Bs[brow][bcol4] = bv;
        } else {
            #pragma unroll
            for (int j = 0; j < 4; j++) {
                int n = n0 + bcol4 + j;
                Bs[brow][bcol4 + j] = (n < Ndim) ? Bbase[(size_t)(k0 + brow) * ldb + bcol4 + j] : 0.f;
            }
        }
        __syncthreads();
        #pragma unroll
        for (int kk = 0; kk < 16; kk++) {
            float a4[4], b4[4];
            #pragma unroll
            for (int i = 0; i < 4; i++) a4[i] = As[kk][ty * 4 + i];
            #pragma unroll
            for (int j = 0; j < 4; j++) b4[j] = Bs[kk][tx * 4 + j];
            #pragma unroll
            for (int i = 0; i < 4; i++)
                #pragma unroll
                for (int j = 0; j < 4; j++)
                    acc[i][j] += a4[i] * b4[j];
        }
        __syncthreads();
    }
    #pragma unroll
    for (int i = 0; i < 4; i++) {
        int m = m0 + ty * 4 + i;
        #pragma unroll
        for (int j = 0; j < 4; j++) {
            int n = n0 + tx * 4 + j;
            if (n < Ndim) {
                float vout = acc[i][j] + bias[n];
                if (RES) vout += res[(size_t)m * Ndim + n];
                if (RELU) vout = fmaxf(vout, 0.f);
                C[(size_t)m * Ndim + n] = vout;
            }
        }
    }
}

// ---------------- causal attention, one block per (b,h,t) ----------------
// q,k,v,out: [B*T, H*DH] with col = h*64+e
__global__ void attn_kernel(const float* __restrict__ q, const float* __restrict__ k,
                            const float* __restrict__ v, float* __restrict__ out) {
    int idx = blockIdx.x;
    int t  = idx & (TT - 1);
    int bh = idx >> 10;
    int h = bh % HH, b = bh / HH;
    const size_t base = ((size_t)b * TT) * DD + (size_t)h * DHH;
    __shared__ float qs[DHH];
    __shared__ float sc[TT];
    __shared__ float red[256];
    int tid = threadIdx.x;
    if (tid < DHH) qs[tid] = q[base + (size_t)t * DD + tid];
    __syncthreads();
    const float scale = 0.125f;   // 1/sqrt(64)
    float lmax = -1e30f;
    for (int s = tid; s <= t; s += 256) {
        const float* kr = k + base + (size_t)s * DD;
        float dot = 0.f;
        #pragma unroll
        for (int e = 0; e < DHH; e += 4) {
            float4 kv4 = *(const float4*)(kr + e);
            dot += qs[e] * kv4.x + qs[e + 1] * kv4.y + qs[e + 2] * kv4.z + qs[e + 3] * kv4.w;
        }
        dot *= scale;
        sc[s] = dot;
        lmax = fmaxf(lmax, dot);
    }
    red[tid] = lmax; __syncthreads();
    for (int w = 128; w > 0; w >>= 1) { if (tid < w) red[tid] = fmaxf(red[tid], red[tid + w]); __syncthreads(); }
    float m = red[0];
    __syncthreads();
    float lsum = 0.f;
    for (int s = tid; s <= t; s += 256) { float p = expf(sc[s] - m); sc[s] = p; lsum += p; }
    red[tid] = lsum; __syncthreads();
    for (int w = 128; w > 0; w >>= 1) { if (tid < w) red[tid] += red[tid + w]; __syncthreads(); }
    float inv = 1.f / red[0];
    __syncthreads();
    int e = tid & 63, grp = tid >> 6;
    float acc = 0.f;
    for (int s = grp; s <= t; s += 4) acc += sc[s] * v[base + (size_t)s * DD + e];
    red[tid] = acc; __syncthreads();
    if (tid < 64) {
        float o = (red[tid] + red[tid + 64] + red[tid + 128] + red[tid + 192]) * inv;
        out[base + (size_t)t * DD + e] = o;
    }
}

extern "C" void kernel_launch(void* const* d_in, const int* in_sizes, int n_in,
                              void* d_out, int out_size, void* d_ws, size_t ws_size,
                              hipStream_t stream) {
    const int*   tokens = (const int*)  d_in[0];
    const float* emb    = (const float*)d_in[1];
    const float* wq     = (const float*)d_in[2];
    const float* bq     = (const float*)d_in[3];
    const float* wk     = (const float*)d_in[4];
    const float* bk     = (const float*)d_in[5];
    const float* wv     = (const float*)d_in[6];
    const float* bv     = (const float*)d_in[7];
    const float* wo     = (const float*)d_in[8];
    const float* bo     = (const float*)d_in[9];
    const float* ln1_g  = (const float*)d_in[10];
    const float* ln1_b  = (const float*)d_in[11];
    const float* ln2_g  = (const float*)d_in[12];
    const float* ln2_b  = (const float*)d_in[13];
    const float* w1     = (const float*)d_in[14];
    const float* b1     = (const float*)d_in[15];
    const float* w2     = (const float*)d_in[16];
    const float* b2     = (const float*)d_in[17];
    const float* rms_w  = (const float*)d_in[18];
    const float* wu     = (const float*)d_in[19];
    const float* bu     = (const float*)d_in[20];
    float* out = (float*)d_out;

    const size_t MD = (size_t)MM * DD;
    float* x  = (float*)d_ws;       // [MM, DD]
    float* xn = x  + MD;            // [MM, DD]
    float* qb = xn + MD;            // [MM, DD]
    float* kb = qb + MD;            // [MM, DD]
    float* vb = kb + MD;            // [MM, DD]
    float* ab = vb + MD;            // [MM, DD]
    float* hb = qb;                 // [MM, FFF] aliases qb..ab (4*MD == MM*FFF)

    embed_kernel<<<MM, 256, 0, stream>>>(tokens, emb, x);

    dim3 gD (DD  / 64, MM / 64);
    dim3 gFF(FFF / 64, MM / 64);
    dim3 gV ((VV + 63) / 64, MM / 64);

    for (int l = 0; l < LL; l++) {
        ln_kernel<<<MM, 256, 0, stream>>>(x, ln1_g + l * DD, ln1_b + l * DD, xn);
        const size_t wqkv_off = (size_t)l * HH * DD * DHH;
        gemm_kernel<true , false, false><<<gD, 256, 0, stream>>>(xn, wq + wqkv_off, bq + l * DD, nullptr, qb, MM, DD, DD);
        gemm_kernel<true , false, false><<<gD, 256, 0, stream>>>(xn, wk + wqkv_off, bk + l * DD, nullptr, kb, MM, DD, DD);
        gemm_kernel<true , false, false><<<gD, 256, 0, stream>>>(xn, wv + wqkv_off, bv + l * DD, nullptr, vb, MM, DD, DD);
        attn_kernel<<<BB * HH * TT, 256, 0, stream>>>(qb, kb, vb, ab);
        gemm_kernel<false, false, true ><<<gD, 256, 0, stream>>>(ab, wo + (size_t)l * DD * DD, bo + l * DD, x, x, MM, DD, DD);
        ln_kernel<<<MM, 256, 0, stream>>>(x, ln2_g + l * DD, ln2_b + l * DD, xn);
        gemm_kernel<false, true , false><<<gFF, 256, 0, stream>>>(xn, w1 + (size_t)l * DD * FFF, b1 + l * FFF, nullptr, hb, MM, FFF, DD);
        gemm_kernel<false, false, true ><<<gD, 256, 0, stream>>>(hb, w2 + (size_t)l * FFF * DD, b2 + l * DD, x, x, MM, DD, FFF);
    }

    rms_kernel<<<MM, 256, 0, stream>>>(x, rms_w, xn);
    gemm_kernel<false, false, false><<<gV, 256, 0, stream>>>(xn, wu, bu, nullptr, out, MM, VV, DD);
}